// Round 18
// baseline (498.733 us; speedup 1.0000x reference)
//
#include <hip/hip_runtime.h>
#include <hip/hip_bf16.h>

typedef __hip_bfloat16 bf16;
typedef __attribute__((ext_vector_type(8))) short s16x8;
typedef __attribute__((ext_vector_type(4))) float f32x4;

constexpr int cN = 128, cC = 64, cT = 64, cV = 25, cK = 3, cMID = 64, cKM = 192, cTV = 1600;
constexpr float cEPS = 1e-5f;

// BSS intermediates (no d_ws use). All rewritten before read each call.
__device__ float g_tmp[cN * cC * cV];
// Per-channel Adyn in B-fragment order: [n][r][nf(2)][lane(64)][j(8)] bf16
__device__ ushort g_adF[(size_t)cN * cKM * 1024];          // 50.3 MB
// Folded weights in A-fragment order: [k-step][m-frag(12)][lane(64)][8]
__device__ ushort g_WpreF[2 * 12 * 512];
__device__ ushort g_WcatF[8 * 12 * 512];
__device__ float g_bpre [cKM];
__device__ float g_cterm[cKM];

__device__ __forceinline__ ushort f2bu(float v){ return __builtin_bit_cast(ushort, __float2bfloat16(v)); }

// Zl fragment index with bank swizzle: XOR oct's low 2 bits into col bits 1..2.
__device__ __forceinline__ int zidx(int oct, int col){
  return (oct*128 + (col ^ ((oct & 3) << 1))) * 8;
}

// ---------------------------------------------------------------------------
// 1) g_tmp[n,c,v] = mean_t x[n,c,t,v]  (grid = N*16) + blocks 0..7 also fold
//    bn into weights/biases (A-frag order) as a side job.   (r15 verbatim)
// ---------------------------------------------------------------------------
__global__ __launch_bounds__(256) void gm_tmp(const float* __restrict__ x,
    const float* __restrict__ Wpre, const float* __restrict__ bpre,
    const float* __restrict__ bnpre,
    const float* __restrict__ Wpost, const float* __restrict__ bpost,
    const float* __restrict__ bnpost,
    const float* __restrict__ Wdown, const float* __restrict__ bdown,
    const float* __restrict__ bndown){
  __shared__ float xs[4 * cTV];
  int n = blockIdx.x >> 4, cg = blockIdx.x & 15;
  int tid = threadIdx.x;
  const float* xp = x + ((size_t)n*cC + cg*4)*cTV;
  for (int i = tid; i < 4*cTV; i += 256) xs[i] = xp[i];
  __syncthreads();
  if (tid < 100){
    int c = tid / 25, v = tid - c*25;
    float s = 0.f;
    #pragma unroll
    for (int t = 0; t < cT; ++t) s += xs[c*cTV + t*cV + v];
    g_tmp[(n*cC + cg*4 + c)*cV + v] = s * (1.f/cT);
  }
  if (blockIdx.x >= 8) return;
  __syncthreads();
  float* sPre  = xs;
  float* sPost = xs + 32;
  float* sDown = xs + 64;
  int ob = blockIdx.x * 24;
  if (tid < 24){
    int o = ob + tid;
    float sp = bnpre[o] * rsqrtf(bnpre[3*cKM+o] + cEPS);
    sPre[tid] = sp;
    g_bpre[o] = bpre[o]*sp + bnpre[cKM+o] - bnpre[2*cKM+o]*sp;
    float sP = bnpost[o] * rsqrtf(bnpost[3*cKM+o] + cEPS);
    float sD = bndown[o] * rsqrtf(bndown[3*cKM+o] + cEPS);
    sPost[tid] = sP; sDown[tid] = sD;
    g_cterm[o] = bpost[o]*sP + bnpost[cKM+o] - bnpost[2*cKM+o]*sP
               + bdown[o]*sD + bndown[cKM+o] - bndown[2*cKM+o]*sD;
  }
  __syncthreads();
  for (int i = tid; i < 24*cC; i += 256){
    int ol = i >> 6, k = i & 63;
    int o = ob + ol;
    int step = k >> 5, g = (k >> 3) & 3, j = k & 7;
    int dst = ((step*12 + (o>>4)) << 9) + (((g<<4) | (o&15)) << 3) + j;
    g_WpreF[dst] = f2bu(Wpre[o*cC + k] * sPre[ol]);
  }
  for (int i = tid; i < 24*256; i += 256){
    int ol = i >> 8, k = i & 255;
    int o = ob + ol;
    float w = (k < cKM) ? Wpost[o*cKM + k] * sPost[ol]
                        : Wdown[o*cC + (k - cKM)] * sDown[ol];
    int step = k >> 5, g = (k >> 3) & 3, j = k & 7;
    int dst = ((step*12 + (o>>4)) << 9) + (((g<<4) | (o&15)) << 3) + j;
    g_WcatF[dst] = f2bu(w);
  }
}

// ---------------------------------------------------------------------------
// 2) PREP: x1x2 -> gram -> softmax -> adF assembly.  grid = N*3, 512 thr.
//    (r15 verbatim)
// ---------------------------------------------------------------------------
__global__ __launch_bounds__(512) void gm_prep(
    const float* __restrict__ W1, const float* __restrict__ b1,
    const float* __restrict__ W2, const float* __restrict__ b2,
    const float* __restrict__ A,  const float* __restrict__ alpha,
    const float* __restrict__ beta){
  __shared__ float tl [cC*cV + 32];
  __shared__ float w1l[cMID*65];
  __shared__ float w2l[cMID*65];
  __shared__ float x1l[cMID*cV];
  __shared__ float x2l[cMID*cV];
  __shared__ float Al [cV*cV];
  __shared__ float adal[cV*cV];
  int bid = blockIdx.x; int n = bid / 3, kg = bid % 3;
  int tid = threadIdx.x;
  for (int i = tid; i < cC*cV; i += 512) tl[i] = g_tmp[n*cC*cV + i];
  if (tid < 32) tl[cC*cV + tid] = 0.f;
  for (int i = tid; i < cV*cV; i += 512) Al[i] = A[kg*625 + i];
  for (int i = tid; i < cMID*cC; i += 512){
    int ch = i >> 6, c = i & 63;
    w1l[ch*65 + c] = W1[(kg*cMID + ch)*cC + c];
    w2l[ch*65 + c] = W2[(kg*cMID + ch)*cC + c];
  }
  __syncthreads();
  {
    int ch = tid >> 3, iv = tid & 7;
    int o = kg*cMID + ch;
    float bb1 = b1[o], bb2 = b2[o];
    float s1[4] = {bb1, bb1, bb1, bb1};
    float s2[4] = {bb2, bb2, bb2, bb2};
    #pragma unroll 8
    for (int c = 0; c < cC; ++c){
      float w1c = w1l[ch*65 + c], w2c = w2l[ch*65 + c];
      #pragma unroll
      for (int k = 0; k < 4; ++k){
        float t = tl[c*cV + iv + 8*k];
        s1[k] += w1c * t;
        s2[k] += w2c * t;
      }
    }
    #pragma unroll
    for (int k = 0; k < 4; ++k){
      int v = iv + 8*k;
      if (v < cV){ x1l[ch*cV + v] = s1[k]; x2l[ch*cV + v] = s2[k]; }
    }
  }
  __syncthreads();
  for (int idx = tid; idx < cV*cV; idx += 512){
    int v = idx / cV, w = idx % cV;
    float s = 0.f;
    #pragma unroll 8
    for (int c = 0; c < cMID; ++c) s += x1l[c*cV + v] * x2l[c*cV + w];
    adal[idx] = s;
  }
  __syncthreads();
  float b0 = beta[0];
  if (tid < cV){
    int w = tid;
    float m = -1e30f;
    for (int v = 0; v < cV; ++v) m = fmaxf(m, adal[v*cV + w]);
    float s = 0.f;
    for (int v = 0; v < cV; ++v) s += __expf(adal[v*cV + w] - m);
    float inv = b0 / s;
    for (int v = 0; v < cV; ++v) adal[v*cV + w] = __expf(adal[v*cV + w] - m) * inv;
  }
  __syncthreads();
  for (int i = tid; i < cV*cV; i += 512) Al[i] += adal[i];
  __syncthreads();
  float a0 = alpha[0];
  int rem = tid * 2;
  int nf = rem >> 9, r2 = rem & 511;
  int li = r2 >> 3, j0 = r2 & 7;
  int v0 = 8*(li >> 4) + j0, w = 16*nf + (li & 15);
  bool wok = (w < cV);
  bool v0ok = wok && (v0 < cV), v1ok = wok && (v0 + 1 < cV);
  float AW0 = v0ok ? Al[v0*cV + w] : 0.f;
  float AW1 = v1ok ? Al[(v0+1)*cV + w] : 0.f;
  uint* dst = (uint*)(g_adF + ((size_t)n*cKM + kg*cMID)*1024 + rem);
  #pragma unroll 4
  for (int ch = 0; ch < cMID; ++ch){
    float f0 = 0.f, f1 = 0.f;
    if (wok){
      float xw = x2l[ch*cV + w];
      if (v0ok){
        float e2 = __expf(2.f*(x1l[ch*cV + v0] - xw));
        f0 = __fdividef(e2 - 1.f, e2 + 1.f)*a0 + AW0;
      }
      if (v1ok){
        float e2 = __expf(2.f*(x1l[ch*cV + v0 + 1] - xw));
        f1 = __fdividef(e2 - 1.f, e2 + 1.f)*a0 + AW1;
      }
    }
    dst[(size_t)ch * 512] = (uint)f2bu(f0) | ((uint)f2bu(f1) << 16);
  }
}

// ---------------------------------------------------------------------------
// 3) FUSED pre -> per-channel map -> out.  One block per (n, 4-t tile).
//    r18: GEMM3 interleaved into the kg loop (a3 accumulates across kg) so
//    Zl holds only 8 y-octets (current kg) + 8 x-octets = 32 KB; total LDS
//    48 KB -> 3 blocks/CU (was 2).  K-step order identical to r15.
//    bva1 loaded inline in GEMM2 (r16-validated) to stay under 85 VGPR.
// ---------------------------------------------------------------------------
__global__ __launch_bounds__(512, 6) void gm_fused(const float* __restrict__ x,
                                                   float* __restrict__ outf){
  __shared__ ushort Zl[16 * 128 * 8];      // 32 KB: oct 0..7 = y(kg), 8..15 = x
  __shared__ ushort Pt[64 * 128];          // 16 KB [chl][slot][t][8]
  // n-contiguous XCD swizzle: an n's 16 blocks land consecutively on ONE XCD
  int c8 = (int)blockIdx.x & 7, i8 = (int)blockIdx.x >> 3;
  int n = c8 + 8*(i8 >> 4), ttile = i8 & 15;
  int t0 = ttile * 4;
  int tid = threadIdx.x;
  int wv = tid >> 6, lane = tid & 63, g = lane >> 4, l15 = lane & 15;
  int mfh = wv >> 1;          // 0..3
  int nfh = wv & 1;           // 0..1

  // ---- stage x -> Z octets 8..15 (pads zero); never overwritten ----
  #pragma unroll
  for (int s0 = 0; s0 < 1024; s0 += 512){
    int s = s0 + tid;
    int oct = 8 + (s >> 7), col = s & 127;
    int t = col >> 5, v = col & 31;
    ushort u[8];
    if (v < cV){
      const float* xp = x + ((size_t)n*cC + (oct-8)*8)*cTV + (t0 + t)*cV + v;
      #pragma unroll
      for (int j = 0; j < 8; ++j) u[j] = f2bu(xp[(size_t)j*cTV]);
    } else {
      #pragma unroll
      for (int j = 0; j < 8; ++j) u[j] = 0;
    }
    *(uint4*)&Zl[zidx(oct, col)] = *(const uint4*)u;
  }

  // ---- persistent GEMM3 accumulators ----
  f32x4 a3[3][4];
  #pragma unroll
  for (int mm = 0; mm < 3; ++mm)
    #pragma unroll
    for (int nn = 0; nn < 4; ++nn) a3[mm][nn] = (f32x4){0.f,0.f,0.f,0.f};

  #pragma unroll 1
  for (int kg = 0; kg < 3; ++kg){
    __syncthreads();   // kg=0: x staged; kg>0: Pt + y-octets safe to overwrite
    const ushort* bpBase = g_adF + ((size_t)n*cKM + kg*64 + wv*8)*1024;
    // ---- prefetch bva0 (8 frags); bva1 loaded inline in GEMM2 ----
    s16x8 bva0[8];
    #pragma unroll
    for (int cc = 0; cc < 8; ++cc)
      bva0[cc] = *(const s16x8*)(bpBase + cc*1024 + lane*8);
    // ---- GEMM1: pre rows kg*64..+63, 128 cols (reads x octets 8..15) ----
    f32x4 a1[4];
    #pragma unroll
    for (int nn = 0; nn < 4; ++nn) a1[nn] = (f32x4){0.f,0.f,0.f,0.f};
    #pragma unroll
    for (int ks = 0; ks < 2; ++ks){
      s16x8 av = *(const s16x8*)(g_WpreF + ((ks*12 + kg*4 + mfh) << 9) + lane*8);
      #pragma unroll
      for (int nn = 0; nn < 4; ++nn){
        int col = 16*(nfh*4 + nn) + l15;
        s16x8 bv = *(const s16x8*)&Zl[zidx(8 + ks*4 + g, col)];
        a1[nn] = __builtin_amdgcn_mfma_f32_16x16x32_bf16(av, bv, a1[nn], 0, 0, 0);
      }
    }
    // bias+relu -> Pt (zero pads), XOR-swizzled slot
    #pragma unroll
    for (int nn = 0; nn < 4; ++nn){
      int col = 16*(nfh*4 + nn) + l15;
      int t = col >> 5, v = col & 31;
      #pragma unroll
      for (int q = 0; q < 4; ++q){
        int o = 16*mfh + 4*g + q;
        float val = (v < cV) ? fmaxf(a1[nn][q] + g_bpre[kg*64 + o], 0.f) : 0.f;
        int slot = ((v>>3) ^ (o>>2)) & 3;
        Pt[o*128 + slot*32 + t*8 + (v & 7)] = f2bu(val);
      }
    }
    __syncthreads();
    // ---- GEMM2 per channel-pair -> y octets 0..7 (octY = wv) ----
    #pragma unroll
    for (int cc = 0; cc < 8; cc += 2){
      int chlE = wv*8 + cc, chlO = chlE + 1;
      s16x8 avE, avO;
      if (l15 < 4){
        int slotE = (g ^ (chlE>>2)) & 3;
        avE = *(const s16x8*)&Pt[chlE*128 + slotE*32 + l15*8];
        avO = *(const s16x8*)&Pt[chlO*128 + slotE*32 + l15*8];  // same slot
      } else { avE = (s16x8){0,0,0,0,0,0,0,0}; avO = avE; }
      s16x8 b1e = *(const s16x8*)(bpBase + cc*1024     + 512 + lane*8);
      s16x8 b1o = *(const s16x8*)(bpBase + (cc+1)*1024 + 512 + lane*8);
      f32x4 d0e = __builtin_amdgcn_mfma_f32_16x16x32_bf16(avE, bva0[cc],   (f32x4){0.f,0.f,0.f,0.f}, 0, 0, 0);
      f32x4 d1e = __builtin_amdgcn_mfma_f32_16x16x32_bf16(avE, b1e,        (f32x4){0.f,0.f,0.f,0.f}, 0, 0, 0);
      f32x4 d0o = __builtin_amdgcn_mfma_f32_16x16x32_bf16(avO, bva0[cc+1], (f32x4){0.f,0.f,0.f,0.f}, 0, 0, 0);
      f32x4 d1o = __builtin_amdgcn_mfma_f32_16x16x32_bf16(avO, b1o,        (f32x4){0.f,0.f,0.f,0.f}, 0, 0, 0);
      if (g == 0){
        #pragma unroll
        for (int q = 0; q < 4; ++q){       // q = t
          uint p0 = (uint)f2bu(d0e[q]) | ((uint)f2bu(d0o[q]) << 16);
          uint p1 = (uint)f2bu(d1e[q]) | ((uint)f2bu(d1o[q]) << 16);
          *(uint*)&Zl[zidx(wv, q*32 + l15)      + cc] = p0;
          *(uint*)&Zl[zidx(wv, q*32 + 16 + l15) + cc] = p1;
        }
      }
    }
    __syncthreads();
    // ---- GEMM3 partial: k-steps kg*2, kg*2+1 over this kg's y octets ----
    #pragma unroll
    for (int ks2 = 0; ks2 < 2; ++ks2){
      int ks3 = kg*2 + ks2;
      s16x8 avc[3], bv[4];
      #pragma unroll
      for (int mm = 0; mm < 3; ++mm)
        avc[mm] = *(const s16x8*)(g_WcatF + ((ks3*12 + mfh*3 + mm) << 9) + lane*8);
      #pragma unroll
      for (int nn = 0; nn < 4; ++nn){
        int col = 16*(nfh*4 + nn) + l15;
        bv[nn] = *(const s16x8*)&Zl[zidx(ks2*4 + g, col)];
      }
      #pragma unroll
      for (int mm = 0; mm < 3; ++mm)
        #pragma unroll
        for (int nn = 0; nn < 4; ++nn)
          a3[mm][nn] = __builtin_amdgcn_mfma_f32_16x16x32_bf16(avc[mm], bv[nn], a3[mm][nn], 0, 0, 0);
    }
  }
  // ---- GEMM3 x-part: k-steps 6,7 over x octets 8..15 (read-only, no sync) ----
  #pragma unroll
  for (int ks2 = 0; ks2 < 2; ++ks2){
    int ks3 = 6 + ks2;
    s16x8 avc[3], bv[4];
    #pragma unroll
    for (int mm = 0; mm < 3; ++mm)
      avc[mm] = *(const s16x8*)(g_WcatF + ((ks3*12 + mfh*3 + mm) << 9) + lane*8);
    #pragma unroll
    for (int nn = 0; nn < 4; ++nn){
      int col = 16*(nfh*4 + nn) + l15;
      bv[nn] = *(const s16x8*)&Zl[zidx(8 + ks2*4 + g, col)];
    }
    #pragma unroll
    for (int mm = 0; mm < 3; ++mm)
      #pragma unroll
      for (int nn = 0; nn < 4; ++nn)
        a3[mm][nn] = __builtin_amdgcn_mfma_f32_16x16x32_bf16(avc[mm], bv[nn], a3[mm][nn], 0, 0, 0);
  }
  // ---- epilogue: bias + relu -> d_out (f32) ----
  #pragma unroll
  for (int mm = 0; mm < 3; ++mm){
    #pragma unroll
    for (int q = 0; q < 4; ++q){
      int o = 48*mfh + 16*mm + 4*g + q;
      float ct = g_cterm[o];
      #pragma unroll
      for (int nn = 0; nn < 4; ++nn){
        int col = 16*(nfh*4 + nn) + l15;
        int t = col >> 5, v = col & 31;
        if (v < cV)
          outf[((size_t)n*cKM + o)*cTV + (t0 + t)*cV + v] = fmaxf(a3[mm][nn][q] + ct, 0.f);
      }
    }
  }
}

// ---------------------------------------------------------------------------
extern "C" void kernel_launch(void* const* d_in, const int* in_sizes, int n_in,
                              void* d_out, int out_size, void* d_ws, size_t ws_size,
                              hipStream_t stream){
  (void)in_sizes; (void)n_in; (void)out_size; (void)d_ws; (void)ws_size;
  const float* x      = (const float*)d_in[0];
  const float* A      = (const float*)d_in[1];
  const float* alpha  = (const float*)d_in[2];
  const float* beta   = (const float*)d_in[3];
  const float* W_pre  = (const float*)d_in[4];
  const float* b_pre  = (const float*)d_in[5];
  const float* bn_pre = (const float*)d_in[6];
  const float* W1     = (const float*)d_in[7];
  const float* b1     = (const float*)d_in[8];
  const float* W2     = (const float*)d_in[9];
  const float* b2     = (const float*)d_in[10];
  const float* W_post = (const float*)d_in[11];
  const float* b_post = (const float*)d_in[12];
  const float* bn_post= (const float*)d_in[13];
  const float* W_down = (const float*)d_in[14];
  const float* b_down = (const float*)d_in[15];
  const float* bn_down= (const float*)d_in[16];
  float* out = (float*)d_out;

  gm_tmp  <<<cN * 16,  256, 0, stream>>>(x, W_pre, b_pre, bn_pre,
                                         W_post, b_post, bn_post,
                                         W_down, b_down, bn_down);
  gm_prep <<<cN * 3,   512, 0, stream>>>(W1, b1, W2, b2, A, alpha, beta);
  gm_fused<<<cN * 16,  512, 0, stream>>>(x, out);
}

// Round 19
// 161.139 us; speedup vs baseline: 3.0951x; 3.0951x over previous
//
#include <hip/hip_runtime.h>
#include <hip/hip_bf16.h>

typedef __hip_bfloat16 bf16;
typedef __attribute__((ext_vector_type(8))) short s16x8;
typedef __attribute__((ext_vector_type(4))) float f32x4;

constexpr int cN = 128, cC = 64, cT = 64, cV = 25, cK = 3, cMID = 64, cKM = 192, cTV = 1600;
constexpr float cEPS = 1e-5f;

// BSS intermediates (no d_ws use). All rewritten before read each call.
__device__ float g_tmp[cN * cC * cV];
// Per-channel Adyn in B-fragment order: [n][r][nf(2)][lane(64)][j(8)] bf16
__device__ ushort g_adF[(size_t)cN * cKM * 1024];          // 50.3 MB
// Folded weights in A-fragment order: [k-step][m-frag(12)][lane(64)][8]
__device__ ushort g_WpreF[2 * 12 * 512];
__device__ ushort g_WcatF[8 * 12 * 512];
__device__ float g_bpre [cKM];
__device__ float g_cterm[cKM];

__device__ __forceinline__ ushort f2bu(float v){ return __builtin_bit_cast(ushort, __float2bfloat16(v)); }

// Zl fragment index with bank swizzle (128-col tile, r15-validated):
// XOR oct's low 2 bits into col bits 1..2.
__device__ __forceinline__ int zidx(int oct, int col){
  return (oct*128 + (col ^ ((oct & 3) << 1))) * 8;
}

// ---------------------------------------------------------------------------
// 1) g_tmp[n,c,v] = mean_t x[n,c,t,v]  (grid = N*16) + blocks 0..7 also fold
//    bn into weights/biases (A-frag order) as a side job.   (r15 verbatim)
// ---------------------------------------------------------------------------
__global__ __launch_bounds__(256) void gm_tmp(const float* __restrict__ x,
    const float* __restrict__ Wpre, const float* __restrict__ bpre,
    const float* __restrict__ bnpre,
    const float* __restrict__ Wpost, const float* __restrict__ bpost,
    const float* __restrict__ bnpost,
    const float* __restrict__ Wdown, const float* __restrict__ bdown,
    const float* __restrict__ bndown){
  __shared__ float xs[4 * cTV];
  int n = blockIdx.x >> 4, cg = blockIdx.x & 15;
  int tid = threadIdx.x;
  const float* xp = x + ((size_t)n*cC + cg*4)*cTV;
  for (int i = tid; i < 4*cTV; i += 256) xs[i] = xp[i];
  __syncthreads();
  if (tid < 100){
    int c = tid / 25, v = tid - c*25;
    float s = 0.f;
    #pragma unroll
    for (int t = 0; t < cT; ++t) s += xs[c*cTV + t*cV + v];
    g_tmp[(n*cC + cg*4 + c)*cV + v] = s * (1.f/cT);
  }
  if (blockIdx.x >= 8) return;
  __syncthreads();
  float* sPre  = xs;
  float* sPost = xs + 32;
  float* sDown = xs + 64;
  int ob = blockIdx.x * 24;
  if (tid < 24){
    int o = ob + tid;
    float sp = bnpre[o] * rsqrtf(bnpre[3*cKM+o] + cEPS);
    sPre[tid] = sp;
    g_bpre[o] = bpre[o]*sp + bnpre[cKM+o] - bnpre[2*cKM+o]*sp;
    float sP = bnpost[o] * rsqrtf(bnpost[3*cKM+o] + cEPS);
    float sD = bndown[o] * rsqrtf(bndown[3*cKM+o] + cEPS);
    sPost[tid] = sP; sDown[tid] = sD;
    g_cterm[o] = bpost[o]*sP + bnpost[cKM+o] - bnpost[2*cKM+o]*sP
               + bdown[o]*sD + bndown[cKM+o] - bndown[2*cKM+o]*sD;
  }
  __syncthreads();
  for (int i = tid; i < 24*cC; i += 256){
    int ol = i >> 6, k = i & 63;
    int o = ob + ol;
    int step = k >> 5, g = (k >> 3) & 3, j = k & 7;
    int dst = ((step*12 + (o>>4)) << 9) + (((g<<4) | (o&15)) << 3) + j;
    g_WpreF[dst] = f2bu(Wpre[o*cC + k] * sPre[ol]);
  }
  for (int i = tid; i < 24*256; i += 256){
    int ol = i >> 8, k = i & 255;
    int o = ob + ol;
    float w = (k < cKM) ? Wpost[o*cKM + k] * sPost[ol]
                        : Wdown[o*cC + (k - cKM)] * sDown[ol];
    int step = k >> 5, g = (k >> 3) & 3, j = k & 7;
    int dst = ((step*12 + (o>>4)) << 9) + (((g<<4) | (o&15)) << 3) + j;
    g_WcatF[dst] = f2bu(w);
  }
}

// ---------------------------------------------------------------------------
// 2) PREP: x1x2 -> gram -> softmax -> adF assembly.
//    r19: grid = N*6 (512 thr): block pairs share (n,kg); each assembles 32
//    channels -> 768 blocks = 3/CU (was 1.5/CU), balanced.  Duplicated
//    gram/softmax is ~3% of block time; per-channel math unchanged.
// ---------------------------------------------------------------------------
__global__ __launch_bounds__(512) void gm_prep(
    const float* __restrict__ W1, const float* __restrict__ b1,
    const float* __restrict__ W2, const float* __restrict__ b2,
    const float* __restrict__ A,  const float* __restrict__ alpha,
    const float* __restrict__ beta){
  __shared__ float tl [cC*cV + 32];
  __shared__ float w1l[cMID*65];
  __shared__ float w2l[cMID*65];
  __shared__ float x1l[cMID*cV];
  __shared__ float x2l[cMID*cV];
  __shared__ float Al [cV*cV];
  __shared__ float adal[cV*cV];
  int bid = blockIdx.x;
  int n = bid / 6, rem6 = bid % 6;
  int kg = rem6 >> 1, half = rem6 & 1;
  int tid = threadIdx.x;
  for (int i = tid; i < cC*cV; i += 512) tl[i] = g_tmp[n*cC*cV + i];
  if (tid < 32) tl[cC*cV + tid] = 0.f;
  for (int i = tid; i < cV*cV; i += 512) Al[i] = A[kg*625 + i];
  for (int i = tid; i < cMID*cC; i += 512){
    int ch = i >> 6, c = i & 63;
    w1l[ch*65 + c] = W1[(kg*cMID + ch)*cC + c];
    w2l[ch*65 + c] = W2[(kg*cMID + ch)*cC + c];
  }
  __syncthreads();
  {
    int ch = tid >> 3, iv = tid & 7;
    int o = kg*cMID + ch;
    float bb1 = b1[o], bb2 = b2[o];
    float s1[4] = {bb1, bb1, bb1, bb1};
    float s2[4] = {bb2, bb2, bb2, bb2};
    #pragma unroll 8
    for (int c = 0; c < cC; ++c){
      float w1c = w1l[ch*65 + c], w2c = w2l[ch*65 + c];
      #pragma unroll
      for (int k = 0; k < 4; ++k){
        float t = tl[c*cV + iv + 8*k];
        s1[k] += w1c * t;
        s2[k] += w2c * t;
      }
    }
    #pragma unroll
    for (int k = 0; k < 4; ++k){
      int v = iv + 8*k;
      if (v < cV){ x1l[ch*cV + v] = s1[k]; x2l[ch*cV + v] = s2[k]; }
    }
  }
  __syncthreads();
  for (int idx = tid; idx < cV*cV; idx += 512){
    int v = idx / cV, w = idx % cV;
    float s = 0.f;
    #pragma unroll 8
    for (int c = 0; c < cMID; ++c) s += x1l[c*cV + v] * x2l[c*cV + w];
    adal[idx] = s;
  }
  __syncthreads();
  float b0 = beta[0];
  if (tid < cV){
    int w = tid;
    float m = -1e30f;
    for (int v = 0; v < cV; ++v) m = fmaxf(m, adal[v*cV + w]);
    float s = 0.f;
    for (int v = 0; v < cV; ++v) s += __expf(adal[v*cV + w] - m);
    float inv = b0 / s;
    for (int v = 0; v < cV; ++v) adal[v*cV + w] = __expf(adal[v*cV + w] - m) * inv;
  }
  __syncthreads();
  for (int i = tid; i < cV*cV; i += 512) Al[i] += adal[i];
  __syncthreads();
  float a0 = alpha[0];
  int rem = tid * 2;
  int nf = rem >> 9, r2 = rem & 511;
  int li = r2 >> 3, j0 = r2 & 7;
  int v0 = 8*(li >> 4) + j0, w = 16*nf + (li & 15);
  bool wok = (w < cV);
  bool v0ok = wok && (v0 < cV), v1ok = wok && (v0 + 1 < cV);
  float AW0 = v0ok ? Al[v0*cV + w] : 0.f;
  float AW1 = v1ok ? Al[(v0+1)*cV + w] : 0.f;
  int ch0 = half * 32;
  uint* dst = (uint*)(g_adF + ((size_t)n*cKM + kg*cMID + ch0)*1024 + rem);
  #pragma unroll 4
  for (int chl = 0; chl < 32; ++chl){
    int ch = ch0 + chl;
    float f0 = 0.f, f1 = 0.f;
    if (wok){
      float xw = x2l[ch*cV + w];
      if (v0ok){
        float e2 = __expf(2.f*(x1l[ch*cV + v0] - xw));
        f0 = __fdividef(e2 - 1.f, e2 + 1.f)*a0 + AW0;
      }
      if (v1ok){
        float e2 = __expf(2.f*(x1l[ch*cV + v0 + 1] - xw));
        f1 = __fdividef(e2 - 1.f, e2 + 1.f)*a0 + AW1;
      }
    }
    dst[(size_t)chl * 512] = (uint)f2bu(f0) | ((uint)f2bu(f1) << 16);
  }
}

// ---------------------------------------------------------------------------
// 3) FUSED pre -> per-channel map -> out.  One block per (n, 4-t tile).
//    512 thr = 8 waves.  LDS 80 KB -> 2 blocks/CU.   (r15 verbatim)
// ---------------------------------------------------------------------------
__global__ __launch_bounds__(512, 4) void gm_fused(const float* __restrict__ x,
                                                   float* __restrict__ outf){
  __shared__ ushort Zl[32 * 128 * 8];      // 64 KB [oct][col^swz][j]
  __shared__ ushort Pt[64 * 128];          // 16 KB [chl][slot][t][8]
  // n-contiguous XCD swizzle: an n's 16 blocks land consecutively on ONE XCD
  int c8 = (int)blockIdx.x & 7, i8 = (int)blockIdx.x >> 3;
  int n = c8 + 8*(i8 >> 4), ttile = i8 & 15;
  int t0 = ttile * 4;
  int tid = threadIdx.x;
  int wv = tid >> 6, lane = tid & 63, g = lane >> 4, l15 = lane & 15;
  int mfh = wv >> 1;          // 0..3
  int nfh = wv & 1;           // 0..1

  // ---- stage x -> Z octets 24..31 (pads zero) ----
  #pragma unroll
  for (int s0 = 0; s0 < 1024; s0 += 512){
    int s = s0 + tid;
    int oct = 24 + (s >> 7), col = s & 127;
    int t = col >> 5, v = col & 31;
    ushort u[8];
    if (v < cV){
      const float* xp = x + ((size_t)n*cC + (oct-24)*8)*cTV + (t0 + t)*cV + v;
      #pragma unroll
      for (int j = 0; j < 8; ++j) u[j] = f2bu(xp[(size_t)j*cTV]);
    } else {
      #pragma unroll
      for (int j = 0; j < 8; ++j) u[j] = 0;
    }
    *(uint4*)&Zl[zidx(oct, col)] = *(const uint4*)u;
  }

  #pragma unroll 1
  for (int kg = 0; kg < 3; ++kg){
    __syncthreads();   // kg=0: x staged; kg>0: Pt safe to overwrite
    // ---- prefetch this kg's adF B-frags (hidden under GEMM1; L2-hot) ----
    s16x8 bva0[8], bva1[8];
    #pragma unroll
    for (int cc = 0; cc < 8; ++cc){
      const ushort* bp = g_adF + ((size_t)n*cKM + kg*64 + wv*8 + cc)*1024;
      bva0[cc] = *(const s16x8*)(bp + lane*8);
      bva1[cc] = *(const s16x8*)(bp + 512 + lane*8);
    }
    // ---- GEMM1: pre rows kg*64..kg*64+63, 128 cols ----
    f32x4 a1[4];
    #pragma unroll
    for (int nn = 0; nn < 4; ++nn) a1[nn] = (f32x4){0.f,0.f,0.f,0.f};
    #pragma unroll
    for (int ks = 0; ks < 2; ++ks){
      s16x8 av = *(const s16x8*)(g_WpreF + ((ks*12 + kg*4 + mfh) << 9) + lane*8);
      #pragma unroll
      for (int nn = 0; nn < 4; ++nn){
        int col = 16*(nfh*4 + nn) + l15;
        s16x8 bv = *(const s16x8*)&Zl[zidx(24 + ks*4 + g, col)];
        a1[nn] = __builtin_amdgcn_mfma_f32_16x16x32_bf16(av, bv, a1[nn], 0, 0, 0);
      }
    }
    // bias+relu -> Pt (zero pads), XOR-swizzled slot
    #pragma unroll
    for (int nn = 0; nn < 4; ++nn){
      int col = 16*(nfh*4 + nn) + l15;
      int t = col >> 5, v = col & 31;
      #pragma unroll
      for (int q = 0; q < 4; ++q){
        int o = 16*mfh + 4*g + q;
        float val = (v < cV) ? fmaxf(a1[nn][q] + g_bpre[kg*64 + o], 0.f) : 0.f;
        int slot = ((v>>3) ^ (o>>2)) & 3;
        Pt[o*128 + slot*32 + t*8 + (v & 7)] = f2bu(val);
      }
    }
    __syncthreads();
    // ---- GEMM2 per channel-pair: D[t(pad16), w] = pre[t,v] @ Adyn[v,w] ----
    int octY = kg*8 + wv;                  // this wave's y octet
    #pragma unroll
    for (int cc = 0; cc < 8; cc += 2){
      int chlE = wv*8 + cc, chlO = chlE + 1;
      s16x8 avE, avO;
      if (l15 < 4){
        int slotE = (g ^ (chlE>>2)) & 3;
        avE = *(const s16x8*)&Pt[chlE*128 + slotE*32 + l15*8];
        avO = *(const s16x8*)&Pt[chlO*128 + slotE*32 + l15*8];  // same slot
      } else { avE = (s16x8){0,0,0,0,0,0,0,0}; avO = avE; }
      f32x4 d0e = __builtin_amdgcn_mfma_f32_16x16x32_bf16(avE, bva0[cc],   (f32x4){0.f,0.f,0.f,0.f}, 0, 0, 0);
      f32x4 d1e = __builtin_amdgcn_mfma_f32_16x16x32_bf16(avE, bva1[cc],   (f32x4){0.f,0.f,0.f,0.f}, 0, 0, 0);
      f32x4 d0o = __builtin_amdgcn_mfma_f32_16x16x32_bf16(avO, bva0[cc+1], (f32x4){0.f,0.f,0.f,0.f}, 0, 0, 0);
      f32x4 d1o = __builtin_amdgcn_mfma_f32_16x16x32_bf16(avO, bva1[cc+1], (f32x4){0.f,0.f,0.f,0.f}, 0, 0, 0);
      if (g == 0){
        #pragma unroll
        for (int q = 0; q < 4; ++q){       // q = t
          uint p0 = (uint)f2bu(d0e[q]) | ((uint)f2bu(d0o[q]) << 16);
          uint p1 = (uint)f2bu(d1e[q]) | ((uint)f2bu(d1o[q]) << 16);
          *(uint*)&Zl[zidx(octY, q*32 + l15)      + cc] = p0;
          *(uint*)&Zl[zidx(octY, q*32 + 16 + l15) + cc] = p1;
        }
      }
    }
  }
  __syncthreads();
  // ---- GEMM3: out[192][128] = Wcat[192][256] @ Z, rotated av prefetch ----
  f32x4 a3[3][4];
  #pragma unroll
  for (int mm = 0; mm < 3; ++mm)
    #pragma unroll
    for (int nn = 0; nn < 4; ++nn) a3[mm][nn] = (f32x4){0.f,0.f,0.f,0.f};
  s16x8 avc[3], avn[3];
  #pragma unroll
  for (int mm = 0; mm < 3; ++mm)
    avc[mm] = *(const s16x8*)(g_WcatF + ((0*12 + mfh*3 + mm) << 9) + lane*8);
  #pragma unroll 1
  for (int ks = 0; ks < 8; ++ks){
    if (ks < 7){
      #pragma unroll
      for (int mm = 0; mm < 3; ++mm)
        avn[mm] = *(const s16x8*)(g_WcatF + (((ks+1)*12 + mfh*3 + mm) << 9) + lane*8);
    }
    s16x8 bv[4];
    #pragma unroll
    for (int nn = 0; nn < 4; ++nn){
      int col = 16*(nfh*4 + nn) + l15;
      bv[nn] = *(const s16x8*)&Zl[zidx(ks*4 + g, col)];
    }
    #pragma unroll
    for (int mm = 0; mm < 3; ++mm)
      #pragma unroll
      for (int nn = 0; nn < 4; ++nn)
        a3[mm][nn] = __builtin_amdgcn_mfma_f32_16x16x32_bf16(avc[mm], bv[nn], a3[mm][nn], 0, 0, 0);
    #pragma unroll
    for (int mm = 0; mm < 3; ++mm) avc[mm] = avn[mm];
  }
  // epilogue: bias + relu -> d_out (f32)
  #pragma unroll
  for (int mm = 0; mm < 3; ++mm){
    #pragma unroll
    for (int q = 0; q < 4; ++q){
      int o = 48*mfh + 16*mm + 4*g + q;
      float ct = g_cterm[o];
      #pragma unroll
      for (int nn = 0; nn < 4; ++nn){
        int col = 16*(nfh*4 + nn) + l15;
        int t = col >> 5, v = col & 31;
        if (v < cV)
          outf[((size_t)n*cKM + o)*cTV + (t0 + t)*cV + v] = fmaxf(a3[mm][nn][q] + ct, 0.f);
      }
    }
  }
}

// ---------------------------------------------------------------------------
extern "C" void kernel_launch(void* const* d_in, const int* in_sizes, int n_in,
                              void* d_out, int out_size, void* d_ws, size_t ws_size,
                              hipStream_t stream){
  (void)in_sizes; (void)n_in; (void)out_size; (void)d_ws; (void)ws_size;
  const float* x      = (const float*)d_in[0];
  const float* A      = (const float*)d_in[1];
  const float* alpha  = (const float*)d_in[2];
  const float* beta   = (const float*)d_in[3];
  const float* W_pre  = (const float*)d_in[4];
  const float* b_pre  = (const float*)d_in[5];
  const float* bn_pre = (const float*)d_in[6];
  const float* W1     = (const float*)d_in[7];
  const float* b1     = (const float*)d_in[8];
  const float* W2     = (const float*)d_in[9];
  const float* b2     = (const float*)d_in[10];
  const float* W_post = (const float*)d_in[11];
  const float* b_post = (const float*)d_in[12];
  const float* bn_post= (const float*)d_in[13];
  const float* W_down = (const float*)d_in[14];
  const float* b_down = (const float*)d_in[15];
  const float* bn_down= (const float*)d_in[16];
  float* out = (float*)d_out;

  gm_tmp  <<<cN * 16,  256, 0, stream>>>(x, W_pre, b_pre, bn_pre,
                                         W_post, b_post, bn_post,
                                         W_down, b_down, bn_down);
  gm_prep <<<cN * 6,   512, 0, stream>>>(W1, b1, W2, b2, A, alpha, beta);
  gm_fused<<<cN * 16,  512, 0, stream>>>(x, out);
}

// Round 20
// 160.512 us; speedup vs baseline: 3.1071x; 1.0039x over previous
//
#include <hip/hip_runtime.h>
#include <hip/hip_bf16.h>

typedef __hip_bfloat16 bf16;
typedef __attribute__((ext_vector_type(8))) short s16x8;
typedef __attribute__((ext_vector_type(4))) float f32x4;

constexpr int cN = 128, cC = 64, cT = 64, cV = 25, cK = 3, cMID = 64, cKM = 192, cTV = 1600;
constexpr float cEPS = 1e-5f;

// BSS intermediates (no d_ws use). All rewritten before read each call.
__device__ float g_tmp[cN * cC * cV];
// Per-channel Adyn in B-fragment order: [n][r][nf(2)][lane(64)][j(8)] bf16
__device__ ushort g_adF[(size_t)cN * cKM * 1024];          // 50.3 MB
// Folded weights in A-fragment order: [k-step][m-frag(12)][lane(64)][8]
__device__ ushort g_WpreF[2 * 12 * 512];
__device__ ushort g_WcatF[8 * 12 * 512];
__device__ float g_bpre [cKM];
__device__ float g_cterm[cKM];

__device__ __forceinline__ ushort f2bu(float v){ return __builtin_bit_cast(ushort, __float2bfloat16(v)); }

// Zl fragment index with bank swizzle (128-col tile, r15-validated):
// XOR oct's low 2 bits into col bits 1..2.
__device__ __forceinline__ int zidx(int oct, int col){
  return (oct*128 + (col ^ ((oct & 3) << 1))) * 8;
}

// ---------------------------------------------------------------------------
// 1) g_tmp[n,c,v] = mean_t x[n,c,t,v]  (grid = N*16) + blocks 0..7 also fold
//    bn into weights/biases.  r20: x staged via float4 (G13).
// ---------------------------------------------------------------------------
__global__ __launch_bounds__(256) void gm_tmp(const float* __restrict__ x,
    const float* __restrict__ Wpre, const float* __restrict__ bpre,
    const float* __restrict__ bnpre,
    const float* __restrict__ Wpost, const float* __restrict__ bpost,
    const float* __restrict__ bnpost,
    const float* __restrict__ Wdown, const float* __restrict__ bdown,
    const float* __restrict__ bndown){
  __shared__ float xs[4 * cTV];
  int n = blockIdx.x >> 4, cg = blockIdx.x & 15;
  int tid = threadIdx.x;
  const float* xp = x + ((size_t)n*cC + cg*4)*cTV;
  // 6400 floats = 1600 float4 (both 16B-aligned: offsets are multiples of 6400B)
  for (int i = tid; i < 1600; i += 256)
    ((float4*)xs)[i] = ((const float4*)xp)[i];
  __syncthreads();
  if (tid < 100){
    int c = tid / 25, v = tid - c*25;
    float s = 0.f;
    #pragma unroll
    for (int t = 0; t < cT; ++t) s += xs[c*cTV + t*cV + v];
    g_tmp[(n*cC + cg*4 + c)*cV + v] = s * (1.f/cT);
  }
  if (blockIdx.x >= 8) return;
  __syncthreads();
  float* sPre  = xs;
  float* sPost = xs + 32;
  float* sDown = xs + 64;
  int ob = blockIdx.x * 24;
  if (tid < 24){
    int o = ob + tid;
    float sp = bnpre[o] * rsqrtf(bnpre[3*cKM+o] + cEPS);
    sPre[tid] = sp;
    g_bpre[o] = bpre[o]*sp + bnpre[cKM+o] - bnpre[2*cKM+o]*sp;
    float sP = bnpost[o] * rsqrtf(bnpost[3*cKM+o] + cEPS);
    float sD = bndown[o] * rsqrtf(bndown[3*cKM+o] + cEPS);
    sPost[tid] = sP; sDown[tid] = sD;
    g_cterm[o] = bpost[o]*sP + bnpost[cKM+o] - bnpost[2*cKM+o]*sP
               + bdown[o]*sD + bndown[cKM+o] - bndown[2*cKM+o]*sD;
  }
  __syncthreads();
  for (int i = tid; i < 24*cC; i += 256){
    int ol = i >> 6, k = i & 63;
    int o = ob + ol;
    int step = k >> 5, g = (k >> 3) & 3, j = k & 7;
    int dst = ((step*12 + (o>>4)) << 9) + (((g<<4) | (o&15)) << 3) + j;
    g_WpreF[dst] = f2bu(Wpre[o*cC + k] * sPre[ol]);
  }
  for (int i = tid; i < 24*256; i += 256){
    int ol = i >> 8, k = i & 255;
    int o = ob + ol;
    float w = (k < cKM) ? Wpost[o*cKM + k] * sPost[ol]
                        : Wdown[o*cC + (k - cKM)] * sDown[ol];
    int step = k >> 5, g = (k >> 3) & 3, j = k & 7;
    int dst = ((step*12 + (o>>4)) << 9) + (((g<<4) | (o&15)) << 3) + j;
    g_WcatF[dst] = f2bu(w);
  }
}

// ---------------------------------------------------------------------------
// 2) PREP: x1x2 -> gram -> softmax -> adF assembly.  grid = N*6 (r19 verbatim)
// ---------------------------------------------------------------------------
__global__ __launch_bounds__(512) void gm_prep(
    const float* __restrict__ W1, const float* __restrict__ b1,
    const float* __restrict__ W2, const float* __restrict__ b2,
    const float* __restrict__ A,  const float* __restrict__ alpha,
    const float* __restrict__ beta){
  __shared__ float tl [cC*cV + 32];
  __shared__ float w1l[cMID*65];
  __shared__ float w2l[cMID*65];
  __shared__ float x1l[cMID*cV];
  __shared__ float x2l[cMID*cV];
  __shared__ float Al [cV*cV];
  __shared__ float adal[cV*cV];
  int bid = blockIdx.x;
  int n = bid / 6, rem6 = bid % 6;
  int kg = rem6 >> 1, half = rem6 & 1;
  int tid = threadIdx.x;
  for (int i = tid; i < cC*cV; i += 512) tl[i] = g_tmp[n*cC*cV + i];
  if (tid < 32) tl[cC*cV + tid] = 0.f;
  for (int i = tid; i < cV*cV; i += 512) Al[i] = A[kg*625 + i];
  for (int i = tid; i < cMID*cC; i += 512){
    int ch = i >> 6, c = i & 63;
    w1l[ch*65 + c] = W1[(kg*cMID + ch)*cC + c];
    w2l[ch*65 + c] = W2[(kg*cMID + ch)*cC + c];
  }
  __syncthreads();
  {
    int ch = tid >> 3, iv = tid & 7;
    int o = kg*cMID + ch;
    float bb1 = b1[o], bb2 = b2[o];
    float s1[4] = {bb1, bb1, bb1, bb1};
    float s2[4] = {bb2, bb2, bb2, bb2};
    #pragma unroll 8
    for (int c = 0; c < cC; ++c){
      float w1c = w1l[ch*65 + c], w2c = w2l[ch*65 + c];
      #pragma unroll
      for (int k = 0; k < 4; ++k){
        float t = tl[c*cV + iv + 8*k];
        s1[k] += w1c * t;
        s2[k] += w2c * t;
      }
    }
    #pragma unroll
    for (int k = 0; k < 4; ++k){
      int v = iv + 8*k;
      if (v < cV){ x1l[ch*cV + v] = s1[k]; x2l[ch*cV + v] = s2[k]; }
    }
  }
  __syncthreads();
  for (int idx = tid; idx < cV*cV; idx += 512){
    int v = idx / cV, w = idx % cV;
    float s = 0.f;
    #pragma unroll 8
    for (int c = 0; c < cMID; ++c) s += x1l[c*cV + v] * x2l[c*cV + w];
    adal[idx] = s;
  }
  __syncthreads();
  float b0 = beta[0];
  if (tid < cV){
    int w = tid;
    float m = -1e30f;
    for (int v = 0; v < cV; ++v) m = fmaxf(m, adal[v*cV + w]);
    float s = 0.f;
    for (int v = 0; v < cV; ++v) s += __expf(adal[v*cV + w] - m);
    float inv = b0 / s;
    for (int v = 0; v < cV; ++v) adal[v*cV + w] = __expf(adal[v*cV + w] - m) * inv;
  }
  __syncthreads();
  for (int i = tid; i < cV*cV; i += 512) Al[i] += adal[i];
  __syncthreads();
  float a0 = alpha[0];
  int rem = tid * 2;
  int nf = rem >> 9, r2 = rem & 511;
  int li = r2 >> 3, j0 = r2 & 7;
  int v0 = 8*(li >> 4) + j0, w = 16*nf + (li & 15);
  bool wok = (w < cV);
  bool v0ok = wok && (v0 < cV), v1ok = wok && (v0 + 1 < cV);
  float AW0 = v0ok ? Al[v0*cV + w] : 0.f;
  float AW1 = v1ok ? Al[(v0+1)*cV + w] : 0.f;
  int ch0 = half * 32;
  uint* dst = (uint*)(g_adF + ((size_t)n*cKM + kg*cMID + ch0)*1024 + rem);
  #pragma unroll 4
  for (int chl = 0; chl < 32; ++chl){
    int ch = ch0 + chl;
    float f0 = 0.f, f1 = 0.f;
    if (wok){
      float xw = x2l[ch*cV + w];
      if (v0ok){
        float e2 = __expf(2.f*(x1l[ch*cV + v0] - xw));
        f0 = __fdividef(e2 - 1.f, e2 + 1.f)*a0 + AW0;
      }
      if (v1ok){
        float e2 = __expf(2.f*(x1l[ch*cV + v0 + 1] - xw));
        f1 = __fdividef(e2 - 1.f, e2 + 1.f)*a0 + AW1;
      }
    }
    dst[(size_t)chl * 512] = (uint)f2bu(f0) | ((uint)f2bu(f1) << 16);
  }
}

// ---------------------------------------------------------------------------
// 3) FUSED pre -> per-channel map -> out.  One block per (n, 4-t tile).
//    512 thr = 8 waves.  LDS 80 KB -> 2 blocks/CU.
//    r20: s_setprio(1) around MFMA clusters (T5) — 2 resident blocks sit at
//    different phases, giving the scheduler role diversity to arbitrate.
// ---------------------------------------------------------------------------
__global__ __launch_bounds__(512, 4) void gm_fused(const float* __restrict__ x,
                                                   float* __restrict__ outf){
  __shared__ ushort Zl[32 * 128 * 8];      // 64 KB [oct][col^swz][j]
  __shared__ ushort Pt[64 * 128];          // 16 KB [chl][slot][t][8]
  // n-contiguous XCD swizzle: an n's 16 blocks land consecutively on ONE XCD
  int c8 = (int)blockIdx.x & 7, i8 = (int)blockIdx.x >> 3;
  int n = c8 + 8*(i8 >> 4), ttile = i8 & 15;
  int t0 = ttile * 4;
  int tid = threadIdx.x;
  int wv = tid >> 6, lane = tid & 63, g = lane >> 4, l15 = lane & 15;
  int mfh = wv >> 1;          // 0..3
  int nfh = wv & 1;           // 0..1

  // ---- stage x -> Z octets 24..31 (pads zero) ----
  #pragma unroll
  for (int s0 = 0; s0 < 1024; s0 += 512){
    int s = s0 + tid;
    int oct = 24 + (s >> 7), col = s & 127;
    int t = col >> 5, v = col & 31;
    ushort u[8];
    if (v < cV){
      const float* xp = x + ((size_t)n*cC + (oct-24)*8)*cTV + (t0 + t)*cV + v;
      #pragma unroll
      for (int j = 0; j < 8; ++j) u[j] = f2bu(xp[(size_t)j*cTV]);
    } else {
      #pragma unroll
      for (int j = 0; j < 8; ++j) u[j] = 0;
    }
    *(uint4*)&Zl[zidx(oct, col)] = *(const uint4*)u;
  }

  #pragma unroll 1
  for (int kg = 0; kg < 3; ++kg){
    __syncthreads();   // kg=0: x staged; kg>0: Pt safe to overwrite
    // ---- prefetch this kg's adF B-frags (hidden under GEMM1; L2-hot) ----
    s16x8 bva0[8], bva1[8];
    #pragma unroll
    for (int cc = 0; cc < 8; ++cc){
      const ushort* bp = g_adF + ((size_t)n*cKM + kg*64 + wv*8 + cc)*1024;
      bva0[cc] = *(const s16x8*)(bp + lane*8);
      bva1[cc] = *(const s16x8*)(bp + 512 + lane*8);
    }
    // ---- GEMM1: pre rows kg*64..kg*64+63, 128 cols ----
    f32x4 a1[4];
    #pragma unroll
    for (int nn = 0; nn < 4; ++nn) a1[nn] = (f32x4){0.f,0.f,0.f,0.f};
    __builtin_amdgcn_s_setprio(1);
    #pragma unroll
    for (int ks = 0; ks < 2; ++ks){
      s16x8 av = *(const s16x8*)(g_WpreF + ((ks*12 + kg*4 + mfh) << 9) + lane*8);
      #pragma unroll
      for (int nn = 0; nn < 4; ++nn){
        int col = 16*(nfh*4 + nn) + l15;
        s16x8 bv = *(const s16x8*)&Zl[zidx(24 + ks*4 + g, col)];
        a1[nn] = __builtin_amdgcn_mfma_f32_16x16x32_bf16(av, bv, a1[nn], 0, 0, 0);
      }
    }
    __builtin_amdgcn_s_setprio(0);
    // bias+relu -> Pt (zero pads), XOR-swizzled slot
    #pragma unroll
    for (int nn = 0; nn < 4; ++nn){
      int col = 16*(nfh*4 + nn) + l15;
      int t = col >> 5, v = col & 31;
      #pragma unroll
      for (int q = 0; q < 4; ++q){
        int o = 16*mfh + 4*g + q;
        float val = (v < cV) ? fmaxf(a1[nn][q] + g_bpre[kg*64 + o], 0.f) : 0.f;
        int slot = ((v>>3) ^ (o>>2)) & 3;
        Pt[o*128 + slot*32 + t*8 + (v & 7)] = f2bu(val);
      }
    }
    __syncthreads();
    // ---- GEMM2 per channel-pair: D[t(pad16), w] = pre[t,v] @ Adyn[v,w] ----
    int octY = kg*8 + wv;                  // this wave's y octet
    #pragma unroll
    for (int cc = 0; cc < 8; cc += 2){
      int chlE = wv*8 + cc, chlO = chlE + 1;
      s16x8 avE, avO;
      if (l15 < 4){
        int slotE = (g ^ (chlE>>2)) & 3;
        avE = *(const s16x8*)&Pt[chlE*128 + slotE*32 + l15*8];
        avO = *(const s16x8*)&Pt[chlO*128 + slotE*32 + l15*8];  // same slot
      } else { avE = (s16x8){0,0,0,0,0,0,0,0}; avO = avE; }
      __builtin_amdgcn_s_setprio(1);
      f32x4 d0e = __builtin_amdgcn_mfma_f32_16x16x32_bf16(avE, bva0[cc],   (f32x4){0.f,0.f,0.f,0.f}, 0, 0, 0);
      f32x4 d1e = __builtin_amdgcn_mfma_f32_16x16x32_bf16(avE, bva1[cc],   (f32x4){0.f,0.f,0.f,0.f}, 0, 0, 0);
      f32x4 d0o = __builtin_amdgcn_mfma_f32_16x16x32_bf16(avO, bva0[cc+1], (f32x4){0.f,0.f,0.f,0.f}, 0, 0, 0);
      f32x4 d1o = __builtin_amdgcn_mfma_f32_16x16x32_bf16(avO, bva1[cc+1], (f32x4){0.f,0.f,0.f,0.f}, 0, 0, 0);
      __builtin_amdgcn_s_setprio(0);
      if (g == 0){
        #pragma unroll
        for (int q = 0; q < 4; ++q){       // q = t
          uint p0 = (uint)f2bu(d0e[q]) | ((uint)f2bu(d0o[q]) << 16);
          uint p1 = (uint)f2bu(d1e[q]) | ((uint)f2bu(d1o[q]) << 16);
          *(uint*)&Zl[zidx(octY, q*32 + l15)      + cc] = p0;
          *(uint*)&Zl[zidx(octY, q*32 + 16 + l15) + cc] = p1;
        }
      }
    }
  }
  __syncthreads();
  // ---- GEMM3: out[192][128] = Wcat[192][256] @ Z, rotated av prefetch ----
  f32x4 a3[3][4];
  #pragma unroll
  for (int mm = 0; mm < 3; ++mm)
    #pragma unroll
    for (int nn = 0; nn < 4; ++nn) a3[mm][nn] = (f32x4){0.f,0.f,0.f,0.f};
  s16x8 avc[3], avn[3];
  #pragma unroll
  for (int mm = 0; mm < 3; ++mm)
    avc[mm] = *(const s16x8*)(g_WcatF + ((0*12 + mfh*3 + mm) << 9) + lane*8);
  #pragma unroll 1
  for (int ks = 0; ks < 8; ++ks){
    if (ks < 7){
      #pragma unroll
      for (int mm = 0; mm < 3; ++mm)
        avn[mm] = *(const s16x8*)(g_WcatF + (((ks+1)*12 + mfh*3 + mm) << 9) + lane*8);
    }
    s16x8 bv[4];
    #pragma unroll
    for (int nn = 0; nn < 4; ++nn){
      int col = 16*(nfh*4 + nn) + l15;
      bv[nn] = *(const s16x8*)&Zl[zidx(ks*4 + g, col)];
    }
    __builtin_amdgcn_s_setprio(1);
    #pragma unroll
    for (int mm = 0; mm < 3; ++mm)
      #pragma unroll
      for (int nn = 0; nn < 4; ++nn)
        a3[mm][nn] = __builtin_amdgcn_mfma_f32_16x16x32_bf16(avc[mm], bv[nn], a3[mm][nn], 0, 0, 0);
    __builtin_amdgcn_s_setprio(0);
    #pragma unroll
    for (int mm = 0; mm < 3; ++mm) avc[mm] = avn[mm];
  }
  // epilogue: bias + relu -> d_out (f32)
  #pragma unroll
  for (int mm = 0; mm < 3; ++mm){
    #pragma unroll
    for (int q = 0; q < 4; ++q){
      int o = 48*mfh + 16*mm + 4*g + q;
      float ct = g_cterm[o];
      #pragma unroll
      for (int nn = 0; nn < 4; ++nn){
        int col = 16*(nfh*4 + nn) + l15;
        int t = col >> 5, v = col & 31;
        if (v < cV)
          outf[((size_t)n*cKM + o)*cTV + (t0 + t)*cV + v] = fmaxf(a3[mm][nn][q] + ct, 0.f);
      }
    }
  }
}

// ---------------------------------------------------------------------------
extern "C" void kernel_launch(void* const* d_in, const int* in_sizes, int n_in,
                              void* d_out, int out_size, void* d_ws, size_t ws_size,
                              hipStream_t stream){
  (void)in_sizes; (void)n_in; (void)out_size; (void)d_ws; (void)ws_size;
  const float* x      = (const float*)d_in[0];
  const float* A      = (const float*)d_in[1];
  const float* alpha  = (const float*)d_in[2];
  const float* beta   = (const float*)d_in[3];
  const float* W_pre  = (const float*)d_in[4];
  const float* b_pre  = (const float*)d_in[5];
  const float* bn_pre = (const float*)d_in[6];
  const float* W1     = (const float*)d_in[7];
  const float* b1     = (const float*)d_in[8];
  const float* W2     = (const float*)d_in[9];
  const float* b2     = (const float*)d_in[10];
  const float* W_post = (const float*)d_in[11];
  const float* b_post = (const float*)d_in[12];
  const float* bn_post= (const float*)d_in[13];
  const float* W_down = (const float*)d_in[14];
  const float* b_down = (const float*)d_in[15];
  const float* bn_down= (const float*)d_in[16];
  float* out = (float*)d_out;

  gm_tmp  <<<cN * 16,  256, 0, stream>>>(x, W_pre, b_pre, bn_pre,
                                         W_post, b_post, bn_post,
                                         W_down, b_down, bn_down);
  gm_prep <<<cN * 6,   512, 0, stream>>>(W1, b1, W2, b2, A, alpha, beta);
  gm_fused<<<cN * 16,  512, 0, stream>>>(x, out);
}